// Round 16
// baseline (203.785 us; speedup 1.0000x reference)
//
#include <hip/hip_runtime.h>
#include <stdint.h>

typedef __attribute__((ext_vector_type(4))) int   i32x4;
typedef __attribute__((ext_vector_type(4))) float f32x4;
typedef unsigned char uchar;

#define M_TOT 8192
#define K_TOT 4096
#define N_TOT 4096

#define BM 256
#define BN 256
#define BKB 128                              /* K elems (bytes) per tile */
#define NTILES (K_TOT / BKB)                 /* 32 */
#define NWG ((M_TOT / BM) * (N_TOT / BN))    /* 512 */

#define WS_XQ ((size_t)M_TOT * K_TOT)            /* 33.5 MB i8 x */
#define WS_WQ ((size_t)N_TOT * K_TOT)            /* 16.8 MB i8 w4 */
#define WS_SF ((size_t)M_TOT * 4)
#define WS_AS ((size_t)M_TOT * 4)
#define WS_NEEDED (WS_XQ + WS_WQ + WS_SF + WS_AS)

__device__ __forceinline__ void async_load16(const void* g, void* l) {
    __builtin_amdgcn_global_load_lds(
        (const __attribute__((address_space(1))) void*)g,
        (__attribute__((address_space(3))) void*)l, 16, 0, 0);
}

// ---- pre-pass 1: per row: a=max|x|/127; q=RNE(x/a) i8; S=sum(q) -------------
__global__ __launch_bounds__(256)
void quant_x_kernel(const float* __restrict__ x, uchar* __restrict__ xq,
                    float* __restrict__ Sf, float* __restrict__ Ascale) {
    const int row  = blockIdx.x * 4 + (threadIdx.x >> 6);
    const int lane = threadIdx.x & 63;
    const float* xr = x + (size_t)row * K_TOT;

    float mx = 0.f;
#pragma unroll
    for (int j = 0; j < 4; ++j) {
        const float* p = xr + j * 1024 + lane * 16;
#pragma unroll
        for (int q = 0; q < 4; ++q) {
            f32x4 v = *(const f32x4*)(p + q * 4);
#pragma unroll
            for (int e = 0; e < 4; ++e) mx = fmaxf(mx, fabsf(v[e]));
        }
    }
#pragma unroll
    for (int off = 32; off; off >>= 1) mx = fmaxf(mx, __shfl_xor(mx, off, 64));
    mx = fmaxf(mx, 1e-30f);
    const float a = mx * (1.0f / 127.0f);
    const float inv = 127.0f / mx;

    int sum = 0;
#pragma unroll
    for (int j = 0; j < 4; ++j) {
        const float* p = xr + j * 1024 + lane * 16;
        i32x4 packed;
#pragma unroll
        for (int q = 0; q < 4; ++q) {
            f32x4 v = *(const f32x4*)(p + q * 4);
            uint32_t w = 0;
#pragma unroll
            for (int e = 0; e < 4; ++e) {
                float t = fminf(fmaxf(v[e] * inv, -127.f), 127.f);
                int qi = (int)rintf(t);
                sum += qi;
                w |= ((uint32_t)qi & 255u) << (8 * e);
            }
            packed[q] = (int)w;
        }
        *(i32x4*)(xq + (size_t)row * K_TOT + j * 1024 + lane * 16) = packed;
    }
#pragma unroll
    for (int off = 32; off; off >>= 1) sum += __shfl_xor(sum, off, 64);
    if (lane == 0) { Sf[row] = (float)sum; Ascale[row] = a; }
}

// ---- pre-pass 2: unpack qw nibbles -> W^T i8 [n][k] -------------------------
__global__ __launch_bounds__(256)
void unpack_kernel(const uint32_t* __restrict__ qw, uchar* __restrict__ wq) {
    const int t = blockIdx.x * 256 + threadIdx.x;
    const int n = t & (N_TOT - 1);
    const int g = t >> 12;
#pragma unroll
    for (int j = 0; j < 4; ++j) {
        const uint32_t q = qw[(size_t)(g * 4 + j) * N_TOT + n];
        uint64_t w = 0;
#pragma unroll
        for (int e = 0; e < 8; ++e)
            w |= (uint64_t)((q >> (4 * e)) & 15u) << (8 * e);
        *(uint64_t*)(wq + (size_t)n * K_TOT + g * 32 + j * 8) = w;
    }
}

// ---------------- main GEMM: i8 MFMA 16x16x64, 1 barrier/K-tile --------------
// R16 change vs R15 (arithmetic-identical, i32 exact -> absmax must match):
// M8 is two-pass (all alo-MFMAs, then all ahi-MFMAs) so same-acc updates are
// separated by 3 independent MFMAs (R15 had them ADJACENT -> each 2nd MFMA
// stalled full accumulate latency; counters showed 17.4 cyc/MFMA vs ~5 peak).
// setprio: one pair around the whole cluster (16 toggles pinned the schedule).
__global__ __launch_bounds__(512, 2)
void gemm_i8_kernel(const uchar* __restrict__ xq,
                    const uchar* __restrict__ wq,
                    const float* __restrict__ Sf,
                    const float* __restrict__ Ascale,
                    const float* __restrict__ sc,
                    const uint32_t* __restrict__ qz,
                    const float* __restrict__ bias,
                    float* __restrict__ out)
{
    __shared__ __align__(16) uchar lds[2 * 4 * 16384];   // 128 KiB

    const int tid  = threadIdx.x;
    const int lane = tid & 63;
    const int wave = tid >> 6;
    const int wm = wave >> 2;
    const int wn = wave & 3;
    const int fr = lane & 15;
    const int fk = lane >> 4;

    const int bid = blockIdx.x;
    const int swz = (bid & 7) * (NWG / 8) + (bid >> 3);
    const int m0 = (swz >> 4) * BM;
    const int n0 = (swz & 15) * BN;

    const int srow = tid >> 3;
    const int sch  = ((tid & 7) ^ (srow & 7)) * 16;
    const uchar* gA[2]; const uchar* gB[2];
    gA[0] = xq + (size_t)(m0 + srow) * K_TOT + sch;
    gA[1] = xq + (size_t)(m0 + 128 + srow) * K_TOT + sch;
    gB[0] = wq + (size_t)(n0 + srow) * K_TOT + sch;
    gB[1] = wq + (size_t)(n0 + 128 + srow) * K_TOT + sch;

#define STAGE(tile, r) do {                                                    \
    const int _t = ((tile) <= 31) ? (tile) : ((tile) - 2);                     \
    const uchar* _s = ((r) < 2 ? gA[(r)] : gB[(r) - 2]) + (size_t)_t * BKB;    \
    uchar* _d = lds + ((_t & 1) * 4 + (r)) * 16384 + tid * 16;                 \
    async_load16(_s, _d);                                                      \
    async_load16(_s + (size_t)64 * K_TOT, _d + 8192);                          \
} while (0)

#define LD_AF(dlo, dhi, buf, mf) do {                                          \
    const uchar* _b = lds + ((buf) * 4 + wm) * 16384;                          \
    const int _row = (mf) * 16 + fr;                                           \
    dlo = *(const i32x4*)(_b + _row * 128 + (((fk    ) ^ (_row & 7)) * 16));   \
    dhi = *(const i32x4*)(_b + _row * 128 + (((4 | fk) ^ (_row & 7)) * 16));   \
} while (0)

#define LD_BF(dlo, dhi, buf, nf) do {                                          \
    const uchar* _b = lds + ((buf) * 4 + 2 + (wn >> 1)) * 16384;               \
    const int _row = (wn & 1) * 64 + (nf) * 16 + fr;                           \
    dlo = *(const i32x4*)(_b + _row * 128 + (((fk    ) ^ (_row & 7)) * 16));   \
    dhi = *(const i32x4*)(_b + _row * 128 + (((4 | fk) ^ (_row & 7)) * 16));   \
} while (0)

// two-pass: 4 independent alo-MFMAs, then 4 independent ahi-MFMAs.
// same-acc pair separation = 3 MFMAs (~15-20 cyc) >= accumulate latency.
#define M8(mf, alo, ahi) do {                                                  \
    acc[mf][0] = __builtin_amdgcn_mfma_i32_16x16x64_i8(alo, b0l, acc[mf][0], 0, 0, 0); \
    acc[mf][1] = __builtin_amdgcn_mfma_i32_16x16x64_i8(alo, b1l, acc[mf][1], 0, 0, 0); \
    acc[mf][2] = __builtin_amdgcn_mfma_i32_16x16x64_i8(alo, b2l, acc[mf][2], 0, 0, 0); \
    acc[mf][3] = __builtin_amdgcn_mfma_i32_16x16x64_i8(alo, b3l, acc[mf][3], 0, 0, 0); \
    acc[mf][0] = __builtin_amdgcn_mfma_i32_16x16x64_i8(ahi, b0h, acc[mf][0], 0, 0, 0); \
    acc[mf][1] = __builtin_amdgcn_mfma_i32_16x16x64_i8(ahi, b1h, acc[mf][1], 0, 0, 0); \
    acc[mf][2] = __builtin_amdgcn_mfma_i32_16x16x64_i8(ahi, b2h, acc[mf][2], 0, 0, 0); \
    acc[mf][3] = __builtin_amdgcn_mfma_i32_16x16x64_i8(ahi, b3h, acc[mf][3], 0, 0, 0); \
} while (0)

#define SB() do { asm volatile("" ::: "memory");                               \
    __builtin_amdgcn_s_barrier(); asm volatile("" ::: "memory"); } while (0)
#define VM0    asm volatile("s_waitcnt vmcnt(0)" ::: "memory")
#define LGKM0  asm volatile("s_waitcnt lgkmcnt(0)" ::: "memory")

    i32x4 acc[8][4];
#pragma unroll
    for (int m = 0; m < 8; ++m)
#pragma unroll
        for (int n = 0; n < 4; ++n)
            acc[m][n] = (i32x4){0, 0, 0, 0};

    i32x4 a0l, a0h, a1l, a1h, a2l, a2h;
    i32x4 b0l, b0h, b1l, b1h, b2l, b2h, b3l, b3h;

    STAGE(0, 0); STAGE(0, 1); STAGE(0, 2); STAGE(0, 3);

#define BODY(t, buf) do {                                                      \
    VM0;                                                                       \
    SB();                                                                      \
    LD_BF(b0l, b0h, buf, 0); LD_BF(b1l, b1h, buf, 1);                          \
    LD_BF(b2l, b2h, buf, 2); LD_BF(b3l, b3h, buf, 3);                          \
    LD_AF(a0l, a0h, buf, 0); LD_AF(a1l, a1h, buf, 1); LD_AF(a2l, a2h, buf, 2); \
    STAGE((t) + 1, 0); STAGE((t) + 1, 1); STAGE((t) + 1, 2); STAGE((t) + 1, 3);\
    __builtin_amdgcn_s_setprio(1);                                             \
    M8(0, a0l, a0h); LD_AF(a0l, a0h, buf, 3);                                  \
    M8(1, a1l, a1h); LD_AF(a1l, a1h, buf, 4);                                  \
    M8(2, a2l, a2h); LD_AF(a2l, a2h, buf, 5);                                  \
    M8(3, a0l, a0h); LD_AF(a0l, a0h, buf, 6);                                  \
    M8(4, a1l, a1h); LD_AF(a1l, a1h, buf, 7);                                  \
    M8(5, a2l, a2h);                                                           \
    M8(6, a0l, a0h);                                                           \
    M8(7, a1l, a1h);                                                           \
    __builtin_amdgcn_s_setprio(0);                                             \
    LGKM0;                                                                     \
} while (0)

    for (int i = 0; i < 16; ++i) {
        BODY(2 * i, 0);
        BODY(2 * i + 1, 1);
    }
    VM0;

    // epilogue: y = a[m]*(s*dot - s*(z+1)*S[m]); fp16 round; + fp16 bias
#pragma unroll
    for (int nf = 0; nf < 4; ++nf) {
        const int col = n0 + wn * 64 + nf * 16 + fr;
        const float s = sc[col];
        const uint32_t z4 = (qz[col >> 3] >> ((col & 7) * 4)) & 15u;
        const float zo = s * (float)(z4 + 1u);
        const _Float16 bh = (_Float16)bias[col];
#pragma unroll
        for (int mf = 0; mf < 8; ++mf) {
            const int row0 = m0 + wm * 128 + mf * 16 + fk * 4;
#pragma unroll
            for (int r = 0; r < 4; ++r) {
                const int row = row0 + r;
                const float yv = Ascale[row] *
                    (s * (float)acc[mf][nf][r] - zo * Sf[row]);
                const _Float16 y = (_Float16)yv;
                out[(size_t)row * N_TOT + col] = (float)(_Float16)(y + bh);
            }
        }
    }
#undef STAGE
#undef LD_AF
#undef LD_BF
#undef M8
#undef SB
#undef VM0
#undef LGKM0
#undef BODY
}

// ---------------- fallback (proven correct, slow) ----------------------------
__global__ __launch_bounds__(256)
void qlinf32_kernel(const float* __restrict__ x, const uint32_t* __restrict__ qw,
                    const float* __restrict__ sc, const uint32_t* __restrict__ qz,
                    const float* __restrict__ bias, float* __restrict__ out)
{
    const int idx = blockIdx.x * 256 + threadIdx.x;
    const int n   = idx & (N_TOT - 1);
    const int mb  = (idx >> 12) << 2;
    const float s = sc[n];
    const uint32_t z4 = (qz[n >> 3] >> ((n & 7) * 4)) & 15u;
    const float zoff = (float)(z4 + 1u) * s;
    float acc[4] = {0.f, 0.f, 0.f, 0.f};
    const float* xr = x + (size_t)mb * K_TOT;
    for (int kq = 0; kq < K_TOT / 8; ++kq) {
        const uint32_t q = qw[(size_t)kq * N_TOT + n];
        f32x4 xa[4][2];
#pragma unroll
        for (int r = 0; r < 4; ++r) {
            xa[r][0] = *(const f32x4*)(xr + r * K_TOT + kq * 8);
            xa[r][1] = *(const f32x4*)(xr + r * K_TOT + kq * 8 + 4);
        }
#pragma unroll
        for (int e = 0; e < 8; ++e) {
            const float w = fmaf((float)((q >> (4 * e)) & 15u), s, -zoff);
#pragma unroll
            for (int r = 0; r < 4; ++r)
                acc[r] = fmaf(xa[r][e >> 2][e & 3], w, acc[r]);
        }
    }
    const _Float16 bh = (_Float16)bias[n];
#pragma unroll
    for (int r = 0; r < 4; ++r) {
        _Float16 y = (_Float16)acc[r];
        out[(size_t)(mb + r) * N_TOT + n] = (float)(_Float16)(y + bh);
    }
}

extern "C" void kernel_launch(void* const* d_in, const int* in_sizes, int n_in,
                              void* d_out, int out_size, void* d_ws, size_t ws_size,
                              hipStream_t stream) {
    int ix = -1, iqw = -1, iqz = -1, isc = -1, ibi = -1;
    for (int i = 0; i < n_in; ++i) {
        const int sz = in_sizes[i];
        if      (sz == 33554432) ix  = i;
        else if (sz == 2097152)  iqw = i;
        else if (sz == 512)      iqz = i;
        else if (sz == 4096)     { if (isc < 0) isc = i; else ibi = i; }
    }
    if (ix < 0)  ix = 0;
    if (iqw < 0) iqw = 1;
    if (isc < 0) isc = 2;
    if (iqz < 0) iqz = 3;
    if (ibi < 0) ibi = 4;

    const float*    xv = (const float*)d_in[ix];
    const uint32_t* qw = (const uint32_t*)d_in[iqw];
    const float*    sc = (const float*)d_in[isc];
    const uint32_t* qz = (const uint32_t*)d_in[iqz];
    const float*    bi = (const float*)d_in[ibi];
    float*         out = (float*)d_out;

    if (ws_size < WS_NEEDED) {
        const int blocks = (M_TOT / 4) * N_TOT / 256;
        hipLaunchKernelGGL(qlinf32_kernel, dim3(blocks), dim3(256), 0, stream,
                           xv, qw, sc, qz, bi, out);
        return;
    }

    uchar* xq = (uchar*)d_ws;
    uchar* wq = (uchar*)d_ws + WS_XQ;
    float* Sf = (float*)((uchar*)d_ws + WS_XQ + WS_WQ);
    float* As = (float*)((uchar*)d_ws + WS_XQ + WS_WQ + WS_SF);

    hipLaunchKernelGGL(quant_x_kernel, dim3(M_TOT / 4), dim3(256),
                       0, stream, xv, xq, Sf, As);
    hipLaunchKernelGGL(unpack_kernel, dim3(N_TOT * 128 / 256), dim3(256),
                       0, stream, qw, wq);
    hipLaunchKernelGGL(gemm_i8_kernel, dim3(NWG), dim3(512), 0, stream,
                       xq, wq, Sf, As, sc, qz, bi, out);
}

// Round 17
// 202.840 us; speedup vs baseline: 1.0047x; 1.0047x over previous
//
#include <hip/hip_runtime.h>
#include <stdint.h>

typedef __attribute__((ext_vector_type(4))) int   i32x4;
typedef __attribute__((ext_vector_type(4))) float f32x4;
typedef unsigned char uchar;

#define M_TOT 8192
#define K_TOT 4096
#define N_TOT 4096

#define BM 128
#define BN 128
#define BKB 128                              /* K bytes per body */
#define NTILES (K_TOT / BKB)                 /* 32 */
#define NWG ((M_TOT / BM) * (N_TOT / BN))    /* 64*32 = 2048 */

#define WS_XQ ((size_t)M_TOT * K_TOT)
#define WS_WQ ((size_t)N_TOT * K_TOT)
#define WS_SF ((size_t)M_TOT * 4)
#define WS_AS ((size_t)M_TOT * 4)
#define WS_NEEDED (WS_XQ + WS_WQ + WS_SF + WS_AS)

__device__ __forceinline__ void async_load16(const void* g, void* l) {
    __builtin_amdgcn_global_load_lds(
        (const __attribute__((address_space(1))) void*)g,
        (__attribute__((address_space(3))) void*)l, 16, 0, 0);
}

// ---- pre-pass 1: per row: a=max|x|/127; q=RNE(x/a) i8; S=sum(q) -------------
__global__ __launch_bounds__(256)
void quant_x_kernel(const float* __restrict__ x, uchar* __restrict__ xq,
                    float* __restrict__ Sf, float* __restrict__ Ascale) {
    const int row  = blockIdx.x * 4 + (threadIdx.x >> 6);
    const int lane = threadIdx.x & 63;
    const float* xr = x + (size_t)row * K_TOT;

    float mx = 0.f;
#pragma unroll
    for (int j = 0; j < 4; ++j) {
        const float* p = xr + j * 1024 + lane * 16;
#pragma unroll
        for (int q = 0; q < 4; ++q) {
            f32x4 v = *(const f32x4*)(p + q * 4);
#pragma unroll
            for (int e = 0; e < 4; ++e) mx = fmaxf(mx, fabsf(v[e]));
        }
    }
#pragma unroll
    for (int off = 32; off; off >>= 1) mx = fmaxf(mx, __shfl_xor(mx, off, 64));
    mx = fmaxf(mx, 1e-30f);
    const float a = mx * (1.0f / 127.0f);
    const float inv = 127.0f / mx;

    int sum = 0;
#pragma unroll
    for (int j = 0; j < 4; ++j) {
        const float* p = xr + j * 1024 + lane * 16;
        i32x4 packed;
#pragma unroll
        for (int q = 0; q < 4; ++q) {
            f32x4 v = *(const f32x4*)(p + q * 4);
            uint32_t w = 0;
#pragma unroll
            for (int e = 0; e < 4; ++e) {
                float t = fminf(fmaxf(v[e] * inv, -127.f), 127.f);
                int qi = (int)rintf(t);
                sum += qi;
                w |= ((uint32_t)qi & 255u) << (8 * e);
            }
            packed[q] = (int)w;
        }
        *(i32x4*)(xq + (size_t)row * K_TOT + j * 1024 + lane * 16) = packed;
    }
#pragma unroll
    for (int off = 32; off; off >>= 1) sum += __shfl_xor(sum, off, 64);
    if (lane == 0) { Sf[row] = (float)sum; Ascale[row] = a; }
}

// ---- pre-pass 2: unpack qw nibbles -> W^T i8 [n][k] -------------------------
__global__ __launch_bounds__(256)
void unpack_kernel(const uint32_t* __restrict__ qw, uchar* __restrict__ wq) {
    const int t = blockIdx.x * 256 + threadIdx.x;
    const int n = t & (N_TOT - 1);
    const int g = t >> 12;
#pragma unroll
    for (int j = 0; j < 4; ++j) {
        const uint32_t q = qw[(size_t)(g * 4 + j) * N_TOT + n];
        uint64_t w = 0;
#pragma unroll
        for (int e = 0; e < 8; ++e)
            w |= (uint64_t)((q >> (4 * e)) & 15u) << (8 * e);
        *(uint64_t*)(wq + (size_t)n * K_TOT + g * 32 + j * 8) = w;
    }
}

// ---------------- main GEMM: 128x128 tile, 64 KiB LDS, 2 blocks/CU -----------
// R17 vs R16: tile 256->128, waves 8->4, LDS 128->64 KiB so TWO blocks are
// resident per CU with independent barriers -> one block's MFMA phase overlaps
// the other's LDS phase (m114 mechanism). R16's counters showed strict
// serial-sum of the two pipes (1 block/CU, all waves barrier-locked).
// Same proven pieces: R12 sync skeleton, R15 bit2 lo/hi read pattern,
// XCD swizzle, parity tail clamp. i32 exact -> absmax identical.
__global__ __launch_bounds__(256, 2)
void gemm_i8_kernel(const uchar* __restrict__ xq,
                    const uchar* __restrict__ wq,
                    const float* __restrict__ Sf,
                    const float* __restrict__ Ascale,
                    const float* __restrict__ sc,
                    const uint32_t* __restrict__ qz,
                    const float* __restrict__ bias,
                    float* __restrict__ out)
{
    __shared__ __align__(16) uchar lds[2 * 2 * 16384];   // 64 KiB

    const int tid  = threadIdx.x;
    const int lane = tid & 63;
    const int wave = tid >> 6;          // 0..3
    const int wm = wave >> 1;           // A 64-row half
    const int wn = wave & 1;            // B 64-col half
    const int fr = lane & 15;
    const int fk = lane >> 4;

    const int bid = blockIdx.x;
    const int swz = (bid & 7) * (NWG / 8) + (bid >> 3);   // bijective, 2048%8==0
    const int m0 = (swz >> 5) * BM;
    const int n0 = (swz & 31) * BN;

    const int srow = tid >> 3;                      // 0..31
    const int c16  = ((tid & 7) ^ (srow & 7)) * 16;
    const uchar* gA = xq + (size_t)(m0 + srow) * K_TOT + c16;
    const uchar* gB = wq + (size_t)(n0 + srow) * K_TOT + c16;

#define STAGE(tile, r) do {                                                    \
    const int _t = ((tile) <= 31) ? (tile) : ((tile) - 2);                     \
    const uchar* _g = ((r) ? gB : gA) + (size_t)_t * BKB;                      \
    uchar* _d = lds + (_t & 1) * 32768 + (r) * 16384 + tid * 16;               \
    async_load16(_g, _d);                                                      \
    async_load16(_g + (size_t)32 * K_TOT, _d + 4096);                          \
    async_load16(_g + (size_t)64 * K_TOT, _d + 8192);                          \
    async_load16(_g + (size_t)96 * K_TOT, _d + 12288);                         \
} while (0)

#define LD_AF(dlo, dhi, buf, mf) do {                                          \
    const uchar* _b = lds + (buf) * 32768;                                     \
    const int _row = wm * 64 + (mf) * 16 + fr;                                 \
    dlo = *(const i32x4*)(_b + _row * 128 + (((fk    ) ^ (_row & 7)) * 16));   \
    dhi = *(const i32x4*)(_b + _row * 128 + (((4 | fk) ^ (_row & 7)) * 16));   \
} while (0)

#define LD_BF(dlo, dhi, buf, nf) do {                                          \
    const uchar* _b = lds + (buf) * 32768 + 16384;                             \
    const int _row = wn * 64 + (nf) * 16 + fr;                                 \
    dlo = *(const i32x4*)(_b + _row * 128 + (((fk    ) ^ (_row & 7)) * 16));   \
    dhi = *(const i32x4*)(_b + _row * 128 + (((4 | fk) ^ (_row & 7)) * 16));   \
} while (0)

// two-pass (R16): 4 independent lo-MFMAs then 4 hi-MFMAs
#define M8(mf, alo, ahi) do {                                                  \
    acc[mf][0] = __builtin_amdgcn_mfma_i32_16x16x64_i8(alo, b0l, acc[mf][0], 0, 0, 0); \
    acc[mf][1] = __builtin_amdgcn_mfma_i32_16x16x64_i8(alo, b1l, acc[mf][1], 0, 0, 0); \
    acc[mf][2] = __builtin_amdgcn_mfma_i32_16x16x64_i8(alo, b2l, acc[mf][2], 0, 0, 0); \
    acc[mf][3] = __builtin_amdgcn_mfma_i32_16x16x64_i8(alo, b3l, acc[mf][3], 0, 0, 0); \
    acc[mf][0] = __builtin_amdgcn_mfma_i32_16x16x64_i8(ahi, b0h, acc[mf][0], 0, 0, 0); \
    acc[mf][1] = __builtin_amdgcn_mfma_i32_16x16x64_i8(ahi, b1h, acc[mf][1], 0, 0, 0); \
    acc[mf][2] = __builtin_amdgcn_mfma_i32_16x16x64_i8(ahi, b2h, acc[mf][2], 0, 0, 0); \
    acc[mf][3] = __builtin_amdgcn_mfma_i32_16x16x64_i8(ahi, b3h, acc[mf][3], 0, 0, 0); \
} while (0)

#define SB() do { asm volatile("" ::: "memory");                               \
    __builtin_amdgcn_s_barrier(); asm volatile("" ::: "memory"); } while (0)
#define VM0    asm volatile("s_waitcnt vmcnt(0)" ::: "memory")
#define LGKM0  asm volatile("s_waitcnt lgkmcnt(0)" ::: "memory")

    i32x4 acc[4][4];
#pragma unroll
    for (int m = 0; m < 4; ++m)
#pragma unroll
        for (int n = 0; n < 4; ++n)
            acc[m][n] = (i32x4){0, 0, 0, 0};

    i32x4 a0l, a0h, a1l, a1h, a2l, a2h, a3l, a3h;
    i32x4 b0l, b0h, b1l, b1h, b2l, b2h, b3l, b3h;

    STAGE(0, 0); STAGE(0, 1);

#define BODY(t, buf) do {                                                      \
    VM0;                                                                       \
    SB();                                                                      \
    LD_BF(b0l, b0h, buf, 0); LD_BF(b1l, b1h, buf, 1);                          \
    LD_BF(b2l, b2h, buf, 2); LD_BF(b3l, b3h, buf, 3);                          \
    LD_AF(a0l, a0h, buf, 0); LD_AF(a1l, a1h, buf, 1);                          \
    LD_AF(a2l, a2h, buf, 2); LD_AF(a3l, a3h, buf, 3);                          \
    STAGE((t) + 1, 0); STAGE((t) + 1, 1);                                      \
    __builtin_amdgcn_s_setprio(1);                                             \
    M8(0, a0l, a0h);                                                           \
    M8(1, a1l, a1h);                                                           \
    M8(2, a2l, a2h);                                                           \
    M8(3, a3l, a3h);                                                           \
    __builtin_amdgcn_s_setprio(0);                                             \
    LGKM0;                                                                     \
} while (0)

    for (int i = 0; i < 16; ++i) {
        BODY(2 * i, 0);
        BODY(2 * i + 1, 1);
    }
    VM0;

    // epilogue: y = a[m]*(s*dot - s*(z+1)*S[m]); fp16 round; + fp16 bias
#pragma unroll
    for (int nf = 0; nf < 4; ++nf) {
        const int col = n0 + wn * 64 + nf * 16 + fr;
        const float s = sc[col];
        const uint32_t z4 = (qz[col >> 3] >> ((col & 7) * 4)) & 15u;
        const float zo = s * (float)(z4 + 1u);
        const _Float16 bh = (_Float16)bias[col];
#pragma unroll
        for (int mf = 0; mf < 4; ++mf) {
            const int row0 = m0 + wm * 64 + mf * 16 + fk * 4;
#pragma unroll
            for (int r = 0; r < 4; ++r) {
                const int row = row0 + r;
                const float yv = Ascale[row] *
                    (s * (float)acc[mf][nf][r] - zo * Sf[row]);
                const _Float16 y = (_Float16)yv;
                out[(size_t)row * N_TOT + col] = (float)(_Float16)(y + bh);
            }
        }
    }
#undef STAGE
#undef LD_AF
#undef LD_BF
#undef M8
#undef SB
#undef VM0
#undef LGKM0
#undef BODY
}

// ---------------- fallback (proven correct, slow) ----------------------------
__global__ __launch_bounds__(256)
void qlinf32_kernel(const float* __restrict__ x, const uint32_t* __restrict__ qw,
                    const float* __restrict__ sc, const uint32_t* __restrict__ qz,
                    const float* __restrict__ bias, float* __restrict__ out)
{
    const int idx = blockIdx.x * 256 + threadIdx.x;
    const int n   = idx & (N_TOT - 1);
    const int mb  = (idx >> 12) << 2;
    const float s = sc[n];
    const uint32_t z4 = (qz[n >> 3] >> ((n & 7) * 4)) & 15u;
    const float zoff = (float)(z4 + 1u) * s;
    float acc[4] = {0.f, 0.f, 0.f, 0.f};
    const float* xr = x + (size_t)mb * K_TOT;
    for (int kq = 0; kq < K_TOT / 8; ++kq) {
        const uint32_t q = qw[(size_t)kq * N_TOT + n];
        f32x4 xa[4][2];
#pragma unroll
        for (int r = 0; r < 4; ++r) {
            xa[r][0] = *(const f32x4*)(xr + r * K_TOT + kq * 8);
            xa[r][1] = *(const f32x4*)(xr + r * K_TOT + kq * 8 + 4);
        }
#pragma unroll
        for (int e = 0; e < 8; ++e) {
            const float w = fmaf((float)((q >> (4 * e)) & 15u), s, -zoff);
#pragma unroll
            for (int r = 0; r < 4; ++r)
                acc[r] = fmaf(xa[r][e >> 2][e & 3], w, acc[r]);
        }
    }
    const _Float16 bh = (_Float16)bias[n];
#pragma unroll
    for (int r = 0; r < 4; ++r) {
        _Float16 y = (_Float16)acc[r];
        out[(size_t)(mb + r) * N_TOT + n] = (float)(_Float16)(y + bh);
    }
}

extern "C" void kernel_launch(void* const* d_in, const int* in_sizes, int n_in,
                              void* d_out, int out_size, void* d_ws, size_t ws_size,
                              hipStream_t stream) {
    int ix = -1, iqw = -1, iqz = -1, isc = -1, ibi = -1;
    for (int i = 0; i < n_in; ++i) {
        const int sz = in_sizes[i];
        if      (sz == 33554432) ix  = i;
        else if (sz == 2097152)  iqw = i;
        else if (sz == 512)      iqz = i;
        else if (sz == 4096)     { if (isc < 0) isc = i; else ibi = i; }
    }
    if (ix < 0)  ix = 0;
    if (iqw < 0) iqw = 1;
    if (isc < 0) isc = 2;
    if (iqz < 0) iqz = 3;
    if (ibi < 0) ibi = 4;

    const float*    xv = (const float*)d_in[ix];
    const uint32_t* qw = (const uint32_t*)d_in[iqw];
    const float*    sc = (const float*)d_in[isc];
    const uint32_t* qz = (const uint32_t*)d_in[iqz];
    const float*    bi = (const float*)d_in[ibi];
    float*         out = (float*)d_out;

    if (ws_size < WS_NEEDED) {
        const int blocks = (M_TOT / 4) * N_TOT / 256;
        hipLaunchKernelGGL(qlinf32_kernel, dim3(blocks), dim3(256), 0, stream,
                           xv, qw, sc, qz, bi, out);
        return;
    }

    uchar* xq = (uchar*)d_ws;
    uchar* wq = (uchar*)d_ws + WS_XQ;
    float* Sf = (float*)((uchar*)d_ws + WS_XQ + WS_WQ);
    float* As = (float*)((uchar*)d_ws + WS_XQ + WS_WQ + WS_SF);

    hipLaunchKernelGGL(quant_x_kernel, dim3(M_TOT / 4), dim3(256),
                       0, stream, xv, xq, Sf, As);
    hipLaunchKernelGGL(unpack_kernel, dim3(N_TOT * 128 / 256), dim3(256),
                       0, stream, qw, wq);
    hipLaunchKernelGGL(gemm_i8_kernel, dim3(NWG), dim3(256), 0, stream,
                       xq, wq, Sf, As, sc, qz, bi, out);
}